// Round 1
// baseline (143.051 us; speedup 1.0000x reference)
//
#include <hip/hip_runtime.h>

// Problem: AdditiveMul  (N_Q=2048, N_K=2048, N_HEAD=8, D_HEAD=64)
// out[i,j,h] = softmax_h( relu( dot(q[i,h,:], attn[0,h,0:64]) + dot(k[j,h,:], attn[0,h,64:128]) ) )
// Output: (2048, 2048, 8) f32 = 134 MB -> store-bandwidth bound.
//
// R6: persistent grid-stride softmax.
// Evidence chain: R1 (50% dense, non-NT) 144.6us < R3 (dense, NT) 149.4 <
// R4 (25% dense) 161.0; R5 (dense, non-NT, lane-paired, 1 store/thread) 139.7.
// rocprof R5: top-5 dispatches are all 536MB poison fills @81us (6.6 TB/s) ->
// softmax <80us; controllable part ~59us vs ~21us store roofline. One 16B
// store per short-lived wave (131072 waves) cannot saturate the write path --
// the 6.6 TB/s fill is grid-stride with many stores in flight per thread.
// R6 keeps R5's lane-pair + 100%-dense-store layout but makes each thread do
// 16 f-positions (stride 524288 float4 = multiple of 4096 -> sk float4 is
// loop-invariant, loaded once). 8192 waves, 16 independent stores in flight.
// Also folds *LOG2E into proj (fmax(x,0)*L == fmax(x*L,0) for L>0).

#define N_Q   2048
#define N_K   2048
#define N_HEAD 8
#define D_HEAD 64

// ---------------------------------------------------------------------------
// Kernel 1: sq[i,h] = LOG2E * dot(q[i,h,:], attn[h,0:64]);
//           sk[j,h] = LOG2E * dot(k[j,h,:], attn[h,64:128])
// 8 lanes per (row,head); float4 loads; shuffle-reduce. ~8.4 MB read, ~4 us.
// ---------------------------------------------------------------------------
__global__ __launch_bounds__(256) void proj_kernel(
    const float* __restrict__ q, const float* __restrict__ k,
    const float* __restrict__ attn,
    float* __restrict__ sq, float* __restrict__ sk)
{
    int tid = blockIdx.x * blockDim.x + threadIdx.x;
    int lane8 = tid & 7;
    int pair  = tid >> 3;                 // [0, 2*N_Q*N_HEAD)
    const int PAIRS = N_Q * N_HEAD;
    bool is_k = pair >= PAIRS;
    int p = is_k ? (pair - PAIRS) : pair; // p = row*8 + h
    int h = p & (N_HEAD - 1);

    const float* src = is_k ? k : q;
    const float* a   = attn + h * (2 * D_HEAD) + (is_k ? D_HEAD : 0);

    const float4* s4 = (const float4*)(src + (size_t)p * D_HEAD + lane8 * 8);
    const float4* a4 = (const float4*)(a + lane8 * 8);
    float4 x0 = s4[0], x1 = s4[1];
    float4 w0 = a4[0], w1 = a4[1];
    float sum = x0.x*w0.x + x0.y*w0.y + x0.z*w0.z + x0.w*w0.w
              + x1.x*w1.x + x1.y*w1.y + x1.z*w1.z + x1.w*w1.w;

    sum += __shfl_xor(sum, 1);
    sum += __shfl_xor(sum, 2);
    sum += __shfl_xor(sum, 4);

    if (lane8 == 0) {
        (is_k ? sk : sq)[p] = sum * 1.4426950408889634f;  // fold LOG2E here
    }
}

// ---------------------------------------------------------------------------
// Kernel 2: persistent grid-stride. f indexes float4s of out (8.4M total).
// Thread handles f0 + it*STRIDE, it=0..15. STRIDE % 4096 == 0, so
// t = f & 4095 (the sk float4 index) is loop-invariant -> load kv once.
// Lane pair (2m, 2m+1) = halves 0/1 of the same j; denom via shfl_xor(,1).
// Every wave store instruction is 1 KB contiguous (100% dense).
// ---------------------------------------------------------------------------
#define SM_BLOCKS 2048
#define SM_ITERS  16          // 2048*256*16 == N_Q * 2*N_K  (exact cover)

__global__ __launch_bounds__(256) void softmax_kernel(
    const float* __restrict__ sq, const float* __restrict__ sk,
    float* __restrict__ out)
{
    const int STRIDE = SM_BLOCKS * 256;            // 524288 float4s
    int f0 = blockIdx.x * 256 + threadIdx.x;       // 0 .. 524287
    int t  = f0 & (2 * N_K - 1);                   // loop-invariant
    int half = f0 & 1;

    float4 kv = ((const float4*)sk)[t];            // loaded ONCE
    const float4* sq4 = (const float4*)sq;
    float4* out4 = (float4*)out;

    #pragma unroll
    for (int it = 0; it < SM_ITERS; ++it) {
        int f = f0 + it * STRIDE;
        int i = f >> 12;                           // f / (2*N_K)
        float4 qv = sq4[2 * i + half];             // broadcast, L1/L2 hit

        // inputs pre-scaled by LOG2E; exp(relu(x)) == exp2(fmax(x*L, 0))
        float v0 = __builtin_amdgcn_exp2f(fmaxf(qv.x + kv.x, 0.0f));
        float v1 = __builtin_amdgcn_exp2f(fmaxf(qv.y + kv.y, 0.0f));
        float v2 = __builtin_amdgcn_exp2f(fmaxf(qv.z + kv.z, 0.0f));
        float v3 = __builtin_amdgcn_exp2f(fmaxf(qv.w + kv.w, 0.0f));

        float ps = (v0 + v1) + (v2 + v3);
        float s  = ps + __shfl_xor(ps, 1);         // partner has other 4 heads
        float r  = __builtin_amdgcn_rcpf(s);

        out4[f] = make_float4(v0 * r, v1 * r, v2 * r, v3 * r);
    }
}

extern "C" void kernel_launch(void* const* d_in, const int* in_sizes, int n_in,
                              void* d_out, int out_size, void* d_ws, size_t ws_size,
                              hipStream_t stream) {
    const float* q    = (const float*)d_in[0];
    const float* k    = (const float*)d_in[1];
    const float* attn = (const float*)d_in[2];
    float* out = (float*)d_out;

    float* sq = (float*)d_ws;            // N_Q*N_HEAD floats
    float* sk = sq + N_Q * N_HEAD;       // N_K*N_HEAD floats

    int total_threads = 2 * N_Q * N_HEAD * 8;   // 262144
    proj_kernel<<<dim3(total_threads / 256), dim3(256), 0, stream>>>(q, k, attn, sq, sk);

    softmax_kernel<<<dim3(SM_BLOCKS), dim3(256), 0, stream>>>(sq, sk, out);
}

// Round 2
// 141.920 us; speedup vs baseline: 1.0080x; 1.0080x over previous
//
#include <hip/hip_runtime.h>

// Problem: AdditiveMul  (N_Q=2048, N_K=2048, N_HEAD=8, D_HEAD=64)
// out[i,j,h] = softmax_h( relu( dot(q[i,h,:], attn[0,h,0:64]) + dot(k[j,h,:], attn[0,h,64:128]) ) )
// Output: (2048, 2048, 8) f32 = 134 MB -> store-bandwidth bound in theory.
//
// R7: kill the per-store dependent chain.
// Evidence: R5 (1 store/wave) ~= R6 (16 stores/wave) -> NOT store-issue bound.
//           R4 (4x sparser stores) only +21us -> NOT store-BW bound.
// => limiter is the serial chain per store: load->add->fmax->v_exp(trans)->
//    sum->ds_swizzle(lgkm)->v_rcp->mul->store.
// Identity: exp(relu(sq+sk)) = max(exp(sq)*exp(sk), 1)   [exp monotone]
// -> precompute eq=exp(sq), ek=exp(sk) in proj (32K values). Inner loop has
//    ZERO transcendentals except one rcp: mul+max+sum+dpp+rcp+mul+store.
// -> shfl_xor(,1) replaced by DPP quad_perm(1,0,3,2) (pure VALU, no lgkm).
// -> row index is block-uniform (256 | 4096): readfirstlane -> s_load sq row,
//    select half via cndmask; VMEM pipe carries stores only.

#define N_Q   2048
#define N_K   2048
#define N_HEAD 8
#define D_HEAD 64

// ---------------------------------------------------------------------------
// Kernel 1: eq[i,h] = exp(dot(q[i,h,:], attn[h,0:64]))
//           ek[j,h] = exp(dot(k[j,h,:], attn[h,64:128]))
// 8 lanes per (row,head); float4 loads; shuffle-reduce; exp2 at the end.
// ---------------------------------------------------------------------------
__global__ __launch_bounds__(256) void proj_kernel(
    const float* __restrict__ q, const float* __restrict__ k,
    const float* __restrict__ attn,
    float* __restrict__ eq, float* __restrict__ ek)
{
    int tid = blockIdx.x * blockDim.x + threadIdx.x;
    int lane8 = tid & 7;
    int pair  = tid >> 3;                 // [0, 2*N_Q*N_HEAD)
    const int PAIRS = N_Q * N_HEAD;
    bool is_k = pair >= PAIRS;
    int p = is_k ? (pair - PAIRS) : pair; // p = row*8 + h
    int h = p & (N_HEAD - 1);

    const float* src = is_k ? k : q;
    const float* a   = attn + h * (2 * D_HEAD) + (is_k ? D_HEAD : 0);

    const float4* s4 = (const float4*)(src + (size_t)p * D_HEAD + lane8 * 8);
    const float4* a4 = (const float4*)(a + lane8 * 8);
    float4 x0 = s4[0], x1 = s4[1];
    float4 w0 = a4[0], w1 = a4[1];
    float sum = x0.x*w0.x + x0.y*w0.y + x0.z*w0.z + x0.w*w0.w
              + x1.x*w1.x + x1.y*w1.y + x1.z*w1.z + x1.w*w1.w;

    sum += __shfl_xor(sum, 1);
    sum += __shfl_xor(sum, 2);
    sum += __shfl_xor(sum, 4);

    if (lane8 == 0) {
        // store exp(dot) = exp2(dot * log2(e))
        float e = __builtin_amdgcn_exp2f(sum * 1.4426950408889634f);
        (is_k ? ek : eq)[p] = e;
    }
}

// ---------------------------------------------------------------------------
// Kernel 2: persistent grid-stride. f indexes float4s of out (8.4M total).
// t = f & 4095 loop-invariant -> ek float4 loaded once. Lane pair (2m,2m+1)
// = halves 0/1 of same j; denominator shared via DPP xor-1 (pure VALU).
// Per element: v = max(eq*ek, 1). Every wave store = 1 KB contiguous.
// ---------------------------------------------------------------------------
#define SM_BLOCKS 2048
#define SM_ITERS  16          // 2048*256*16 == N_Q * 2*N_K  (exact cover)

__device__ __forceinline__ float dpp_xor1(float x) {
    // quad_perm(1,0,3,2) = 0xB1 : lane <-> lane^1, VALU-only, no lgkm
    int v = __builtin_amdgcn_mov_dpp(__builtin_bit_cast(int, x), 0xB1, 0xF, 0xF, true);
    return __builtin_bit_cast(float, v);
}

__global__ __launch_bounds__(256) void softmax_kernel(
    const float* __restrict__ eq, const float* __restrict__ ek,
    float* __restrict__ out)
{
    const int STRIDE = SM_BLOCKS * 256;            // 524288 float4s
    int f0 = blockIdx.x * 256 + threadIdx.x;       // 0 .. 524287
    int t  = f0 & (2 * N_K - 1);                   // loop-invariant
    bool h1 = (f0 & 1);                            // which half of the head dim

    float4 kv = ((const float4*)ek)[t];            // loaded ONCE
    const float4* eq4 = (const float4*)eq;
    float4* out4 = (float4*)out;

    #pragma unroll
    for (int it = 0; it < SM_ITERS; ++it) {
        int f = f0 + it * STRIDE;
        // i = f>>12 is uniform across the block (256 divides 4096):
        int row = __builtin_amdgcn_readfirstlane(f >> 12);
        float4 e0 = eq4[2 * row];                  // uniform -> s_load
        float4 e1 = eq4[2 * row + 1];              // uniform -> s_load
        float4 qv = make_float4(h1 ? e1.x : e0.x, h1 ? e1.y : e0.y,
                                h1 ? e1.z : e0.z, h1 ? e1.w : e0.w);

        // exp(relu(sq+sk)) == max(exp(sq)*exp(sk), 1)
        float v0 = fmaxf(qv.x * kv.x, 1.0f);
        float v1 = fmaxf(qv.y * kv.y, 1.0f);
        float v2 = fmaxf(qv.z * kv.z, 1.0f);
        float v3 = fmaxf(qv.w * kv.w, 1.0f);

        float ps = (v0 + v1) + (v2 + v3);
        float s  = ps + dpp_xor1(ps);              // partner has other 4 heads
        float r  = __builtin_amdgcn_rcpf(s);

        out4[f] = make_float4(v0 * r, v1 * r, v2 * r, v3 * r);
    }
}

extern "C" void kernel_launch(void* const* d_in, const int* in_sizes, int n_in,
                              void* d_out, int out_size, void* d_ws, size_t ws_size,
                              hipStream_t stream) {
    const float* q    = (const float*)d_in[0];
    const float* k    = (const float*)d_in[1];
    const float* attn = (const float*)d_in[2];
    float* out = (float*)d_out;

    float* eq = (float*)d_ws;            // N_Q*N_HEAD floats
    float* ek = eq + N_Q * N_HEAD;       // N_K*N_HEAD floats

    int total_threads = 2 * N_Q * N_HEAD * 8;   // 262144
    proj_kernel<<<dim3(total_threads / 256), dim3(256), 0, stream>>>(q, k, attn, eq, ek);

    softmax_kernel<<<dim3(SM_BLOCKS), dim3(256), 0, stream>>>(eq, ek, out);
}